// Round 13
// baseline (289.572 us; speedup 1.0000x reference)
//
#include <hip/hip_runtime.h>
#include <hip/hip_bf16.h>
#include <stdint.h>

#define NN 16384
#define BM 64
#define KHALF 8192
#define BKA 128              // A staged k-depth per group
#define BKB 64               // compute substep k-depth
#define NG1 (KHALF / BKA)    // 64 groups per block
#define NKT1 (KHALF / BKB)   // 128 substeps per block

typedef __attribute__((ext_vector_type(8))) short bf16x8;
typedef __attribute__((ext_vector_type(4))) float f32x4;
typedef __attribute__((ext_vector_type(4))) unsigned short u16x4;
typedef __attribute__((ext_vector_type(8))) unsigned short u16x8;
typedef __attribute__((ext_vector_type(4))) unsigned int u32x4;

__device__ __forceinline__ unsigned short f2bf(float f) {
    uint32_t u = __builtin_bit_cast(uint32_t, f);
    u += 0x7fffu + ((u >> 16) & 1u);   // RNE; inputs are finite
    return (unsigned short)(u >> 16);
}

// Transpose + MFMA-fragment tiling:
// dst element index for (col c, src-row k):
//   ((k>>5)*8 + (c>>4))*512 + (c&15)*32 + (k&31)
// One wave B-fragment (16 cols x 32 k) = contiguous 1 KB.
__global__ __launch_bounds__(256) void prep_transpose(const float* __restrict__ src,
                                                      unsigned short* __restrict__ dstT) {
    __shared__ unsigned short tl[128][66];
    const int t = threadIdx.x;
    const int r0 = blockIdx.x * 64;
#pragma unroll
    for (int i = 0; i < 8; ++i) {
        int idx = i * 256 + t;
        int r = idx >> 5;
        int s = idx & 31;
        f32x4 v = *(const f32x4*)(src + (size_t)(r0 + r) * 128 + s * 4);
#pragma unroll
        for (int j = 0; j < 4; ++j) tl[s * 4 + j][r] = f2bf(v[j]);
    }
    __syncthreads();
    const int c = t >> 1;
    const int half = t & 1;
    const int ktile = (r0 >> 5) + half;          // 32-k tile index
#pragma unroll
    for (int j = 0; j < 4; ++j) {
        u16x8 p;
#pragma unroll
        for (int e = 0; e < 8; ++e) p[e] = tl[c][half * 32 + j * 8 + e];
        size_t dst = ((size_t)ktile * 8 + (c >> 4)) * 512 + (c & 15) * 32 + j * 8;
        *(u16x8*)(dstT + dst) = p;
    }
}

#define MFMA16(a, b, c) __builtin_amdgcn_mfma_f32_16x16x32_bf16(a, b, c, 0, 0, 0)

#define BARRIER() do {                                          \
    asm volatile("s_waitcnt lgkmcnt(0)" ::: "memory");          \
    __builtin_amdgcn_s_barrier();                               \
    __builtin_amdgcn_sched_barrier(0);                          \
} while (0)

// K1: partial S (64 rows, k-half per block) -> atomicAdd into S.
// grid 512: row0 = (b>>1)*64, khalf = b&1. 2 blocks/CU. B direct from L2.
__global__ __launch_bounds__(256, 2) void sage_partial(
    const float* __restrict__ adj,
    const unsigned short* __restrict__ neighT,   // fragment-tiled
    float* __restrict__ S,                       // d_out, pre-zeroed
    float* __restrict__ degW)                    // [NN], pre-zeroed
{
    // LDS 32.25 KB: aL [2][64r][256B] swizzled; epilogue-free kernel.
    __shared__ __align__(16) char smem[32768];
    char* aL = smem;

    const int t = threadIdx.x;
    const int lane = t & 63;
    const int wv = t >> 6;
    const int mt = wv >> 1;
    const int nt = wv & 1;
    const size_t row0 = (size_t)(blockIdx.x >> 1) * BM;
    const size_t koff = (size_t)(blockIdx.x & 1) * KHALF;

    // A staging: thread owns rows ra0 = t>>3 and ra0+32; 8 lanes/row; 4 passes.
    const int ra0 = t >> 3;
    const int asl = t & 7;
    const float* aG0 = adj + (row0 + ra0) * (size_t)NN + koff + asl * 4;
    const float* aG1 = aG0 + (size_t)32 * NN;

    int awz[8];
#pragma unroll
    for (int i = 0; i < 8; ++i) {
        int row = (i < 4) ? ra0 : (ra0 + 32);
        int j = i & 3;
        awz[i] = row * 256 + ((j * 64 + asl * 8) ^ ((row & 7) << 4));
    }

    // B fragment base: lane-invariant tile offset + lane part.
    // frag(ns, ks, kt) = bT + ((kt*2+ks)*8)*512 + ns*512
    const unsigned short* bT = neighT + ((koff >> 5) * 8 + nt * 4) * 512
                               + (lane & 15) * 32 + (lane >> 4) * 8;

    f32x4 acc[2][4];
#pragma unroll
    for (int i = 0; i < 2; ++i)
#pragma unroll
        for (int j = 0; j < 4; ++j) acc[i][j] = (f32x4){0.f, 0.f, 0.f, 0.f};

    float dsum[2] = {0.f, 0.f};

    f32x4 arA[8];
    u32x4 brF[8], brG[8];

#define ISSUE_A(G) do {                                                       \
    _Pragma("unroll")                                                         \
    for (int i = 0; i < 8; ++i) {                                             \
        const float* p = (i < 4 ? aG0 : aG1) + (size_t)(G) * BKA + (i & 3) * 32; \
        arA[i] = __builtin_nontemporal_load((const f32x4*)p);                 \
    }                                                                         \
} while (0)

#define ISSUE_B(BR, KT) do {                                                  \
    _Pragma("unroll")                                                         \
    for (int ns = 0; ns < 4; ++ns)                                            \
        _Pragma("unroll")                                                     \
        for (int ks = 0; ks < 2; ++ks)                                        \
            BR[ns * 2 + ks] = *(const u32x4*)(bT +                            \
                ((size_t)((KT) * 2 + ks) * 8 + ns) * 512);                    \
} while (0)

#define STAGE_A(DST) do {                                                     \
    _Pragma("unroll")                                                         \
    for (int i = 0; i < 8; ++i) {                                             \
        f32x4 v = arA[i];                                                     \
        dsum[i >> 2] += (v[0] + v[1]) + (v[2] + v[3]);                        \
        u16x4 p; p.x = f2bf(v[0]); p.y = f2bf(v[1]);                          \
        p.z = f2bf(v[2]); p.w = f2bf(v[3]);                                   \
        *(u16x4*)((DST) + awz[i]) = p;                                        \
    }                                                                         \
} while (0)

#define COMPUTE(ABASE, SUB, BR) do {                                          \
    const char* aB = (ABASE);                                                 \
    _Pragma("unroll")                                                         \
    for (int ks = 0; ks < 2; ++ks) {                                          \
        bf16x8 af[2];                                                         \
        _Pragma("unroll")                                                     \
        for (int ms = 0; ms < 2; ++ms) {                                      \
            int r = mt * 32 + ms * 16 + (lane & 15);                          \
            int off = r * 256 + (((SUB) * 128 + ks * 64 + (lane >> 4) * 16)   \
                      ^ ((r & 7) << 4));                                      \
            af[ms] = *(const bf16x8*)(aB + off);                              \
        }                                                                     \
        _Pragma("unroll")                                                     \
        for (int ms = 0; ms < 2; ++ms)                                        \
            _Pragma("unroll")                                                 \
            for (int ns = 0; ns < 4; ++ns)                                    \
                acc[ms][ns] = MFMA16(af[ms],                                  \
                    __builtin_bit_cast(bf16x8, BR[ns * 2 + ks]),              \
                    acc[ms][ns]);                                             \
    }                                                                         \
} while (0)

    // prologue: stage A group 0; B substep 0 in regs
    ISSUE_B(brF, 0);
    ISSUE_A(0);
    STAGE_A(aL);
    BARRIER();

    // One barrier per 128-k group (A dbuf); B needs no LDS sync.
    for (int g = 0; g < NG1; ++g) {
        char* aCur = aL + (g & 1) * 16384;
        char* aNxt = aL + ((g & 1) ^ 1) * 16384;
        const bool more = (g + 1 < NG1);
        // s = 0 (kt = 2g)
        ISSUE_B(brG, 2 * g + 1);
        if (more) ISSUE_A(g + 1);
        COMPUTE(aCur, 0, brF);
        // s = 1 (kt = 2g+1)
        if (more) ISSUE_B(brF, 2 * g + 2);
        COMPUTE(aCur, 1, brG);
        if (more) STAGE_A(aNxt);
        BARRIER();
    }

    // partial degree: 8-lane shfl tree, one atomic per row
    dsum[0] += __shfl_xor(dsum[0], 1, 64);
    dsum[0] += __shfl_xor(dsum[0], 2, 64);
    dsum[0] += __shfl_xor(dsum[0], 4, 64);
    dsum[1] += __shfl_xor(dsum[1], 1, 64);
    dsum[1] += __shfl_xor(dsum[1], 2, 64);
    dsum[1] += __shfl_xor(dsum[1], 4, 64);
    if (asl == 0) {
        atomicAdd(&degW[row0 + ra0], dsum[0]);
        atomicAdd(&degW[row0 + ra0 + 32], dsum[1]);
    }

    // partial S -> atomicAdd, coalesced along cols
#pragma unroll
    for (int ms = 0; ms < 2; ++ms)
#pragma unroll
        for (int ns = 0; ns < 4; ++ns)
#pragma unroll
            for (int j = 0; j < 4; ++j) {
                int r = mt * 32 + ms * 16 + (lane >> 4) * 4 + j;
                int c = nt * 64 + ns * 16 + (lane & 15);
                atomicAdd(&S[(row0 + r) * 128 + c], acc[ms][ns][j]);
            }
}

// K2: out = [feat | S/(deg+1)] @ W^T, overwriting S (=d_out) in place.
__global__ __launch_bounds__(256) void sage_epilogue(
    const float* __restrict__ feat,
    const float* __restrict__ W,
    const float* __restrict__ degW,
    float* __restrict__ S)
{
    __shared__ __align__(16) char smem[33024];
    char* dL = smem;                       // [64][512 B] bf16 swizzled
    float* degp = (float*)(smem + 32768);  // [64]

    const int t = threadIdx.x;
    const int lane = t & 63;
    const int wv = t >> 6;
    const int mt = wv >> 1;
    const int nt = wv & 1;
    const size_t row0 = (size_t)blockIdx.x * BM;

    if (t < 64) degp[t] = degW[row0 + t];

#pragma unroll
    for (int i = 0; i < 8; ++i) {
        int idx = i * 256 + t;
        int r = idx >> 5;
        int s = idx & 31;
        f32x4 v = *(const f32x4*)(feat + (row0 + r) * 128 + s * 4);
        u16x4 p; p.x = f2bf(v[0]); p.y = f2bf(v[1]); p.z = f2bf(v[2]); p.w = f2bf(v[3]);
        int off = (r * 512 + s * 8) ^ ((r & 7) << 4);
        *(u16x4*)(dL + off) = p;
    }
    __syncthreads();   // degp visible

#pragma unroll
    for (int i = 0; i < 8; ++i) {
        int idx = i * 256 + t;
        int r = idx >> 5;
        int s = idx & 31;
        f32x4 v = *(const f32x4*)(S + (row0 + r) * 128 + s * 4);
        float inv = 1.0f / (degp[r] + 1.0f);
        u16x4 p; p.x = f2bf(v[0] * inv); p.y = f2bf(v[1] * inv);
        p.z = f2bf(v[2] * inv); p.w = f2bf(v[3] * inv);
        int off = (r * 512 + 256 + s * 8) ^ ((r & 7) << 4);
        *(u16x4*)(dL + off) = p;
    }
    __syncthreads();

    f32x4 acc2[2][4];
#pragma unroll
    for (int i = 0; i < 2; ++i)
#pragma unroll
        for (int j = 0; j < 4; ++j) acc2[i][j] = (f32x4){0.f, 0.f, 0.f, 0.f};

#pragma unroll
    for (int ks = 0; ks < 8; ++ks) {
        bf16x8 af[2], bfr[4];
#pragma unroll
        for (int ms = 0; ms < 2; ++ms) {
            int r = mt * 32 + ms * 16 + (lane & 15);
            int off = r * 512 + ((ks * 64 + (lane >> 4) * 16) ^ ((r & 7) << 4));
            af[ms] = *(const bf16x8*)(dL + off);
        }
#pragma unroll
        for (int ns = 0; ns < 4; ++ns) {
            int c = nt * 64 + ns * 16 + (lane & 15);
            int k0 = ks * 32 + (lane >> 4) * 8;
            f32x4 w0 = *(const f32x4*)(W + (size_t)c * 256 + k0);
            f32x4 w1 = *(const f32x4*)(W + (size_t)c * 256 + k0 + 4);
            u16x8 p;
            p[0] = f2bf(w0[0]); p[1] = f2bf(w0[1]); p[2] = f2bf(w0[2]); p[3] = f2bf(w0[3]);
            p[4] = f2bf(w1[0]); p[5] = f2bf(w1[1]); p[6] = f2bf(w1[2]); p[7] = f2bf(w1[3]);
            bfr[ns] = __builtin_bit_cast(bf16x8, p);
        }
#pragma unroll
        for (int ms = 0; ms < 2; ++ms)
#pragma unroll
            for (int ns = 0; ns < 4; ++ns)
                acc2[ms][ns] = MFMA16(af[ms], bfr[ns], acc2[ms][ns]);
    }

#pragma unroll
    for (int ms = 0; ms < 2; ++ms)
#pragma unroll
        for (int ns = 0; ns < 4; ++ns)
#pragma unroll
            for (int j = 0; j < 4; ++j) {
                int r = mt * 32 + ms * 16 + (lane >> 4) * 4 + j;
                int c = nt * 64 + ns * 16 + (lane & 15);
                S[(row0 + r) * 128 + c] = acc2[ms][ns][j];
            }
}

extern "C" void kernel_launch(void* const* d_in, const int* in_sizes, int n_in,
                              void* d_out, int out_size, void* d_ws, size_t ws_size,
                              hipStream_t stream) {
    const float* adj = (const float*)d_in[0];
    const float* feat = (const float*)d_in[1];
    const float* neigh = (const float*)d_in[2];
    const float* W = (const float*)d_in[3];
    float* S = (float*)d_out;
    unsigned short* neighT = (unsigned short*)d_ws;                 // 4 MiB, tiled
    float* degW = (float*)((char*)d_ws + (size_t)4 * 1024 * 1024);  // 64 KiB

    hipMemsetAsync(d_out, 0, (size_t)NN * 128 * sizeof(float), stream);
    hipMemsetAsync(degW, 0, (size_t)NN * sizeof(float), stream);
    prep_transpose<<<NN / 64, 256, 0, stream>>>(neigh, neighT);
    sage_partial<<<(NN / BM) * 2, 256, 0, stream>>>(adj, neighT, S, degW);
    sage_epilogue<<<NN / BM, 256, 0, stream>>>(feat, W, degW, S);
}

// Round 14
// 224.906 us; speedup vs baseline: 1.2875x; 1.2875x over previous
//
#include <hip/hip_runtime.h>
#include <hip/hip_bf16.h>
#include <stdint.h>

#define NN 16384
#define BM 64
#define KHALF 8192
#define BKA 128              // A staged k-depth per group
#define BKB 64               // compute / B substep k-depth
#define NG1 (KHALF / BKA)    // 64 groups per block
#define NKT1 (KHALF / BKB)   // 128 substeps per block

typedef __attribute__((ext_vector_type(8))) short bf16x8;
typedef __attribute__((ext_vector_type(4))) float f32x4;
typedef __attribute__((ext_vector_type(4))) unsigned short u16x4;
typedef __attribute__((ext_vector_type(8))) unsigned short u16x8;
typedef __attribute__((ext_vector_type(4))) unsigned int u32x4;

__device__ __forceinline__ unsigned short f2bf(float f) {
    uint32_t u = __builtin_bit_cast(uint32_t, f);
    u += 0x7fffu + ((u >> 16) & 1u);   // RNE; inputs are finite
    return (unsigned short)(u >> 16);
}

// Tiled transpose: neighT[c][r] = bf16(neigh[r][c]).
__global__ __launch_bounds__(256) void prep_transpose(const float* __restrict__ src,
                                                      unsigned short* __restrict__ dstT) {
    __shared__ unsigned short tl[128][66];
    const int t = threadIdx.x;
    const int r0 = blockIdx.x * 64;
#pragma unroll
    for (int i = 0; i < 8; ++i) {
        int idx = i * 256 + t;
        int r = idx >> 5;
        int s = idx & 31;
        f32x4 v = *(const f32x4*)(src + (size_t)(r0 + r) * 128 + s * 4);
#pragma unroll
        for (int j = 0; j < 4; ++j) tl[s * 4 + j][r] = f2bf(v[j]);
    }
    __syncthreads();
    const int c = t >> 1;
    const int half = t & 1;
#pragma unroll
    for (int j = 0; j < 4; ++j) {
        u16x8 p;
#pragma unroll
        for (int e = 0; e < 8; ++e) p[e] = tl[c][half * 32 + j * 8 + e];
        *(u16x8*)(dstT + (size_t)c * NN + r0 + half * 32 + j * 8) = p;
    }
}

#define MFMA16(a, b, c) __builtin_amdgcn_mfma_f32_16x16x32_bf16(a, b, c, 0, 0, 0)

#define BARRIER() do {                                          \
    asm volatile("s_waitcnt lgkmcnt(0)" ::: "memory");          \
    __builtin_amdgcn_s_barrier();                               \
    __builtin_amdgcn_sched_barrier(0);                          \
} while (0)

// K1: partial S (64 rows x 128 cols, k-half per block) -> PLAIN stores into
// per-half buffers Sp[half] and degp[half]. grid 512: row0=(b>>1)*64, half=b&1.
__global__ __launch_bounds__(256, 2) void sage_partial(
    const float* __restrict__ adj,
    const unsigned short* __restrict__ neighT,
    float* __restrict__ S01,          // [2][NN][128]
    float* __restrict__ deg01)        // [2][NN]
{
    // LDS 64 KB: aL [2][64r][256B] swizzled, bL [2][128r][128B] swizzled.
    __shared__ __align__(16) char smem[65536];
    char* aL = smem;
    char* bL = smem + 32768;

    const int t = threadIdx.x;
    const int lane = t & 63;
    const int wv = t >> 6;
    const int mt = wv >> 1;
    const int nt = wv & 1;
    const size_t row0 = (size_t)(blockIdx.x >> 1) * BM;
    const int half = blockIdx.x & 1;
    const size_t koff = (size_t)half * KHALF;

    // A staging: 8 lanes/row; thread owns rows ra0 = t>>3 and ra0+32.
    const int ra0 = t >> 3;
    const int asl = t & 7;
    const float* aG0 = adj + (row0 + ra0) * (size_t)NN + koff + asl * 4;
    const float* aG1 = aG0 + (size_t)32 * NN;

    int awz[8];
#pragma unroll
    for (int i = 0; i < 8; ++i) {
        int row = (i < 4) ? ra0 : (ra0 + 32);
        int j = i & 3;
        awz[i] = row * 256 + ((j * 64 + asl * 8) ^ ((row & 7) << 4));
    }

    // B staging: 4 passes of 32 rows.
    const int br0 = t >> 3;
    const int bcs = (t & 7) * 8;
    const unsigned short* bG = neighT + (size_t)br0 * NN + koff + bcs;
    int bwb[4];
#pragma unroll
    for (int i = 0; i < 4; ++i) {
        int br = br0 + 32 * i;
        bwb[i] = (br * 128 + bcs * 2) ^ ((br & 7) << 4);
    }

    f32x4 acc[2][4];
#pragma unroll
    for (int i = 0; i < 2; ++i)
#pragma unroll
        for (int j = 0; j < 4; ++j) acc[i][j] = (f32x4){0.f, 0.f, 0.f, 0.f};

    float dsum[2] = {0.f, 0.f};

    f32x4 arA[8];
    u32x4 br_[4];

#define ISSUE_A(G) do {                                                       \
    _Pragma("unroll")                                                         \
    for (int i = 0; i < 8; ++i) {                                             \
        const float* p = (i < 4 ? aG0 : aG1) + (size_t)(G) * BKA + (i & 3) * 32; \
        arA[i] = __builtin_nontemporal_load((const f32x4*)p);                 \
    }                                                                         \
} while (0)

#define ISSUE_B(KT) do {                                                      \
    _Pragma("unroll")                                                         \
    for (int i = 0; i < 4; ++i)                                               \
        br_[i] = *(const u32x4*)(bG + (size_t)(32 * i) * NN +                 \
                                 (size_t)(KT) * BKB);                         \
} while (0)

#define STAGE_A(DST) do {                                                     \
    _Pragma("unroll")                                                         \
    for (int i = 0; i < 8; ++i) {                                             \
        f32x4 v = arA[i];                                                     \
        dsum[i >> 2] += (v[0] + v[1]) + (v[2] + v[3]);                        \
        u16x4 p; p.x = f2bf(v[0]); p.y = f2bf(v[1]);                          \
        p.z = f2bf(v[2]); p.w = f2bf(v[3]);                                   \
        *(u16x4*)((DST) + awz[i]) = p;                                        \
    }                                                                         \
} while (0)

#define STAGE_B(BUF) do {                                                     \
    char* bW = bL + (BUF) * 16384;                                            \
    _Pragma("unroll")                                                         \
    for (int i = 0; i < 4; ++i)                                               \
        *(u32x4*)(bW + bwb[i]) = br_[i];                                      \
} while (0)

#define COMPUTE(ABASE, SUB, BBUF) do {                                        \
    const char* aB = (ABASE);                                                 \
    const char* bB = bL + (BBUF) * 16384;                                     \
    _Pragma("unroll")                                                         \
    for (int ks = 0; ks < 2; ++ks) {                                          \
        bf16x8 af[2], bfr[4];                                                 \
        _Pragma("unroll")                                                     \
        for (int ms = 0; ms < 2; ++ms) {                                      \
            int r = mt * 32 + ms * 16 + (lane & 15);                          \
            int off = r * 256 + (((SUB) * 128 + ks * 64 + (lane >> 4) * 16)   \
                      ^ ((r & 7) << 4));                                      \
            af[ms] = *(const bf16x8*)(aB + off);                              \
        }                                                                     \
        _Pragma("unroll")                                                     \
        for (int ns = 0; ns < 4; ++ns) {                                      \
            int c = nt * 64 + ns * 16 + (lane & 15);                          \
            int off = c * 128 + ((ks * 64 + (lane >> 4) * 16)                 \
                      ^ ((c & 7) << 4));                                      \
            bfr[ns] = *(const bf16x8*)(bB + off);                             \
        }                                                                     \
        _Pragma("unroll")                                                     \
        for (int ms = 0; ms < 2; ++ms)                                        \
            _Pragma("unroll")                                                 \
            for (int ns = 0; ns < 4; ++ns)                                    \
                acc[ms][ns] = MFMA16(af[ms], bfr[ns], acc[ms][ns]);           \
    }                                                                         \
} while (0)

    // prologue
    ISSUE_B(0);
    ISSUE_A(0);
    STAGE_B(0);
    STAGE_A(aL);
    BARRIER();

    for (int g = 0; g < NG1; ++g) {
        char* aCur = aL + (g & 1) * 16384;
        char* aNxt = aL + ((g & 1) ^ 1) * 16384;
#pragma unroll
        for (int s = 0; s < 2; ++s) {
            const int kt = g * 2 + s;
            if (kt + 1 < NKT1) ISSUE_B(kt + 1);
            if (s == 0 && g + 1 < NG1) ISSUE_A(g + 1);
            COMPUTE(aCur, s, kt & 1);
            if (kt + 1 < NKT1) STAGE_B((kt + 1) & 1);
            if (s == 1 && g + 1 < NG1) STAGE_A(aNxt);
            BARRIER();
        }
    }

    // partial degree: 8-lane shfl tree, plain store per row
    dsum[0] += __shfl_xor(dsum[0], 1, 64);
    dsum[0] += __shfl_xor(dsum[0], 2, 64);
    dsum[0] += __shfl_xor(dsum[0], 4, 64);
    dsum[1] += __shfl_xor(dsum[1], 1, 64);
    dsum[1] += __shfl_xor(dsum[1], 2, 64);
    dsum[1] += __shfl_xor(dsum[1], 4, 64);
    float* degp = deg01 + (size_t)half * NN;
    if (asl == 0) {
        degp[row0 + ra0] = dsum[0];
        degp[row0 + ra0 + 32] = dsum[1];
    }

    // partial S -> plain coalesced stores into this half's buffer
    float* Sp = S01 + (size_t)half * NN * 128;
#pragma unroll
    for (int ms = 0; ms < 2; ++ms)
#pragma unroll
        for (int ns = 0; ns < 4; ++ns)
#pragma unroll
            for (int j = 0; j < 4; ++j) {
                int r = mt * 32 + ms * 16 + (lane >> 4) * 4 + j;
                int c = nt * 64 + ns * 16 + (lane & 15);
                Sp[(row0 + r) * 128 + c] = acc[ms][ns][j];
            }
}

// K2: out = [feat | (S0+S1)/(deg0+deg1+1)] @ W^T -> d_out.
__global__ __launch_bounds__(256) void sage_epilogue(
    const float* __restrict__ feat,
    const float* __restrict__ W,
    const float* __restrict__ S01,
    const float* __restrict__ deg01,
    float* __restrict__ out)
{
    __shared__ __align__(16) char smem[33024];
    char* dL = smem;                       // [64][512 B] bf16 swizzled
    float* degp = (float*)(smem + 32768);  // [64]

    const int t = threadIdx.x;
    const int lane = t & 63;
    const int wv = t >> 6;
    const int mt = wv >> 1;
    const int nt = wv & 1;
    const size_t row0 = (size_t)blockIdx.x * BM;

    if (t < 64) degp[t] = deg01[row0 + t] + deg01[NN + row0 + t];

    // feat -> cols [0,128)
#pragma unroll
    for (int i = 0; i < 8; ++i) {
        int idx = i * 256 + t;
        int r = idx >> 5;
        int s = idx & 31;
        f32x4 v = *(const f32x4*)(feat + (row0 + r) * 128 + s * 4);
        u16x4 p; p.x = f2bf(v[0]); p.y = f2bf(v[1]); p.z = f2bf(v[2]); p.w = f2bf(v[3]);
        int off = (r * 512 + s * 8) ^ ((r & 7) << 4);
        *(u16x4*)(dL + off) = p;
    }
    __syncthreads();   // degp visible

    // (S0+S1)/(deg+1) -> cols [128,256)
#pragma unroll
    for (int i = 0; i < 8; ++i) {
        int idx = i * 256 + t;
        int r = idx >> 5;
        int s = idx & 31;
        size_t o = (row0 + r) * 128 + s * 4;
        f32x4 v0 = *(const f32x4*)(S01 + o);
        f32x4 v1 = *(const f32x4*)(S01 + (size_t)NN * 128 + o);
        float inv = 1.0f / (degp[r] + 1.0f);
        u16x4 p;
        p.x = f2bf((v0[0] + v1[0]) * inv); p.y = f2bf((v0[1] + v1[1]) * inv);
        p.z = f2bf((v0[2] + v1[2]) * inv); p.w = f2bf((v0[3] + v1[3]) * inv);
        int off = (r * 512 + 256 + s * 8) ^ ((r & 7) << 4);
        *(u16x4*)(dL + off) = p;
    }
    __syncthreads();

    f32x4 acc2[2][4];
#pragma unroll
    for (int i = 0; i < 2; ++i)
#pragma unroll
        for (int j = 0; j < 4; ++j) acc2[i][j] = (f32x4){0.f, 0.f, 0.f, 0.f};

#pragma unroll
    for (int ks = 0; ks < 8; ++ks) {
        bf16x8 af[2], bfr[4];
#pragma unroll
        for (int ms = 0; ms < 2; ++ms) {
            int r = mt * 32 + ms * 16 + (lane & 15);
            int off = r * 512 + ((ks * 64 + (lane >> 4) * 16) ^ ((r & 7) << 4));
            af[ms] = *(const bf16x8*)(dL + off);
        }
#pragma unroll
        for (int ns = 0; ns < 4; ++ns) {
            int c = nt * 64 + ns * 16 + (lane & 15);
            int k0 = ks * 32 + (lane >> 4) * 8;
            f32x4 w0 = *(const f32x4*)(W + (size_t)c * 256 + k0);
            f32x4 w1 = *(const f32x4*)(W + (size_t)c * 256 + k0 + 4);
            u16x8 p;
            p[0] = f2bf(w0[0]); p[1] = f2bf(w0[1]); p[2] = f2bf(w0[2]); p[3] = f2bf(w0[3]);
            p[4] = f2bf(w1[0]); p[5] = f2bf(w1[1]); p[6] = f2bf(w1[2]); p[7] = f2bf(w1[3]);
            bfr[ns] = __builtin_bit_cast(bf16x8, p);
        }
#pragma unroll
        for (int ms = 0; ms < 2; ++ms)
#pragma unroll
            for (int ns = 0; ns < 4; ++ns)
                acc2[ms][ns] = MFMA16(af[ms], bfr[ns], acc2[ms][ns]);
    }

#pragma unroll
    for (int ms = 0; ms < 2; ++ms)
#pragma unroll
        for (int ns = 0; ns < 4; ++ns)
#pragma unroll
            for (int j = 0; j < 4; ++j) {
                int r = mt * 32 + ms * 16 + (lane >> 4) * 4 + j;
                int c = nt * 64 + ns * 16 + (lane & 15);
                out[(row0 + r) * 128 + c] = acc2[ms][ns][j];
            }
}

extern "C" void kernel_launch(void* const* d_in, const int* in_sizes, int n_in,
                              void* d_out, int out_size, void* d_ws, size_t ws_size,
                              hipStream_t stream) {
    const float* adj = (const float*)d_in[0];
    const float* feat = (const float*)d_in[1];
    const float* neigh = (const float*)d_in[2];
    const float* W = (const float*)d_in[3];
    float* out = (float*)d_out;

    // ws layout: neighT 4 MiB | deg01 2*64 KiB | pad | S01 2*8 MiB
    unsigned short* neighT = (unsigned short*)d_ws;
    float* deg01 = (float*)((char*)d_ws + (size_t)4 * 1024 * 1024);
    float* S01 = (float*)((char*)d_ws + (size_t)8 * 1024 * 1024);

    prep_transpose<<<NN / 64, 256, 0, stream>>>(neigh, neighT);
    sage_partial<<<(NN / BM) * 2, 256, 0, stream>>>(adj, neighT, S01, deg01);
    sage_epilogue<<<NN / BM, 256, 0, stream>>>(feat, W, S01, deg01, out);
}

// Round 15
// 195.451 us; speedup vs baseline: 1.4816x; 1.1507x over previous
//
#include <hip/hip_runtime.h>
#include <hip/hip_bf16.h>
#include <stdint.h>

#define NN 16384
#define BM 64
#define KHALF 8192
#define BKA 128              // A staged k-depth per group
#define BKB 64               // compute / B substep k-depth
#define NG1 (KHALF / BKA)    // 64 groups per block
#define NKT1 (KHALF / BKB)   // 128 substeps per block

typedef __attribute__((ext_vector_type(8))) short bf16x8;
typedef __attribute__((ext_vector_type(4))) float f32x4;
typedef __attribute__((ext_vector_type(4))) unsigned short u16x4;
typedef __attribute__((ext_vector_type(8))) unsigned short u16x8;
typedef __attribute__((ext_vector_type(4))) unsigned int u32x4;

typedef __attribute__((address_space(1))) const unsigned int gu32;
typedef __attribute__((address_space(3))) unsigned int lu32;

__device__ __forceinline__ unsigned short f2bf(float f) {
    uint32_t u = __builtin_bit_cast(uint32_t, f);
    u += 0x7fffu + ((u >> 16) & 1u);   // RNE; inputs are finite
    return (unsigned short)(u >> 16);
}

// Tiled transpose: neighT[c][r] = bf16(neigh[r][c]).
__global__ __launch_bounds__(256) void prep_transpose(const float* __restrict__ src,
                                                      unsigned short* __restrict__ dstT) {
    __shared__ unsigned short tl[128][66];
    const int t = threadIdx.x;
    const int r0 = blockIdx.x * 64;
#pragma unroll
    for (int i = 0; i < 8; ++i) {
        int idx = i * 256 + t;
        int r = idx >> 5;
        int s = idx & 31;
        f32x4 v = *(const f32x4*)(src + (size_t)(r0 + r) * 128 + s * 4);
#pragma unroll
        for (int j = 0; j < 4; ++j) tl[s * 4 + j][r] = f2bf(v[j]);
    }
    __syncthreads();
    const int c = t >> 1;
    const int half = t & 1;
#pragma unroll
    for (int j = 0; j < 4; ++j) {
        u16x8 p;
#pragma unroll
        for (int e = 0; e < 8; ++e) p[e] = tl[c][half * 32 + j * 8 + e];
        *(u16x8*)(dstT + (size_t)c * NN + r0 + half * 32 + j * 8) = p;
    }
}

#define MFMA16(a, b, c) __builtin_amdgcn_mfma_f32_16x16x32_bf16(a, b, c, 0, 0, 0)

// K1: partial S (64 rows x 128 cols, k-half per block) -> plain stores.
// grid 512: row0=(b>>1)*64, half=b&1. 2 blocks/CU. B staged via global_load_lds.
__global__ __launch_bounds__(256, 2) void sage_partial(
    const float* __restrict__ adj,
    const unsigned short* __restrict__ neighT,
    float* __restrict__ S01,          // [2][NN][128]
    float* __restrict__ deg01)        // [2][NN]
{
    // LDS 64 KB: aL [2][64r][256B] swizzled, bL [2][128r][128B] swizzled.
    __shared__ __align__(16) char smem[65536];
    char* aL = smem;
    char* bL = smem + 32768;

    const int t = threadIdx.x;
    const int lane = t & 63;
    const int wv = t >> 6;
    const int mt = wv >> 1;
    const int nt = wv & 1;
    const size_t row0 = (size_t)(blockIdx.x >> 1) * BM;
    const int half = blockIdx.x & 1;
    const size_t koff = (size_t)half * KHALF;

    // A staging: 8 lanes/row; thread owns rows ra0 = t>>3 and ra0+32.
    const int ra0 = t >> 3;
    const int asl = t & 7;
    const float* aG0 = adj + (row0 + ra0) * (size_t)NN + koff + asl * 4;
    const float* aG1 = aG0 + (size_t)32 * NN;

    int awz[8];
#pragma unroll
    for (int i = 0; i < 8; ++i) {
        int row = (i < 4) ? ra0 : (ra0 + 32);
        int j = i & 3;
        awz[i] = row * 256 + ((j * 64 + asl * 8) ^ ((row & 7) << 4));
    }

    // B staging via DMA: linear LDS dest (wave-uniform base + lane*16) +
    // inverse-swizzled global source chunk: chunk_g = (t&7) ^ (row&7).
    const int bc = t >> 3;                      // row within 32-row pass
    const int bslot = (t & 7) ^ (bc & 7);       // pre-swizzled source chunk
    const unsigned short* bG2 = neighT + (size_t)bc * NN + koff + bslot * 8;

    f32x4 acc[2][4];
#pragma unroll
    for (int i = 0; i < 2; ++i)
#pragma unroll
        for (int j = 0; j < 4; ++j) acc[i][j] = (f32x4){0.f, 0.f, 0.f, 0.f};

    float dsum[2] = {0.f, 0.f};

    f32x4 arA[8];

#define ISSUE_A(G) do {                                                       \
    _Pragma("unroll")                                                         \
    for (int i = 0; i < 8; ++i) {                                             \
        const float* p = (i < 4 ? aG0 : aG1) + (size_t)(G) * BKA + (i & 3) * 32; \
        arA[i] = __builtin_nontemporal_load((const f32x4*)p);                 \
    }                                                                         \
} while (0)

// 4 DMA ops: pass i covers rows i*32..i*32+31 -> LDS [i*4096, i*4096+4096)
#define ISSUE_B_DMA(KT, BUF) do {                                             \
    char* bW = bL + (BUF) * 16384;                                            \
    _Pragma("unroll")                                                         \
    for (int i = 0; i < 4; ++i) {                                             \
        const unsigned short* gp = bG2 + (size_t)(i * 32) * NN +              \
                                   (size_t)(KT) * BKB;                        \
        void* lp = bW + i * 4096 + wv * 1024;                                 \
        __builtin_amdgcn_global_load_lds((gu32*)gp, (lu32*)lp, 16, 0, 0);     \
    }                                                                         \
} while (0)

#define STAGE_A(DST) do {                                                     \
    _Pragma("unroll")                                                         \
    for (int i = 0; i < 8; ++i) {                                             \
        f32x4 v = arA[i];                                                     \
        dsum[i >> 2] += (v[0] + v[1]) + (v[2] + v[3]);                        \
        u16x4 p; p.x = f2bf(v[0]); p.y = f2bf(v[1]);                          \
        p.z = f2bf(v[2]); p.w = f2bf(v[3]);                                   \
        *(u16x4*)((DST) + awz[i]) = p;                                        \
    }                                                                         \
} while (0)

#define COMPUTE(ABASE, SUB, BBUF) do {                                        \
    const char* aB = (ABASE);                                                 \
    const char* bB = bL + (BBUF) * 16384;                                     \
    _Pragma("unroll")                                                         \
    for (int ks = 0; ks < 2; ++ks) {                                          \
        bf16x8 af[2], bfr[4];                                                 \
        _Pragma("unroll")                                                     \
        for (int ms = 0; ms < 2; ++ms) {                                      \
            int r = mt * 32 + ms * 16 + (lane & 15);                          \
            int off = r * 256 + (((SUB) * 128 + ks * 64 + (lane >> 4) * 16)   \
                      ^ ((r & 7) << 4));                                      \
            af[ms] = *(const bf16x8*)(aB + off);                              \
        }                                                                     \
        _Pragma("unroll")                                                     \
        for (int ns = 0; ns < 4; ++ns) {                                      \
            int c = nt * 64 + ns * 16 + (lane & 15);                          \
            int off = c * 128 + ((ks * 64 + (lane >> 4) * 16)                 \
                      ^ ((c & 7) << 4));                                      \
            bfr[ns] = *(const bf16x8*)(bB + off);                             \
        }                                                                     \
        _Pragma("unroll")                                                     \
        for (int ms = 0; ms < 2; ++ms)                                        \
            _Pragma("unroll")                                                 \
            for (int ns = 0; ns < 4; ++ns)                                    \
                acc[ms][ns] = MFMA16(af[ms], bfr[ns], acc[ms][ns]);           \
    }                                                                         \
} while (0)

    // prologue: B(0) DMA -> buf0; A group 0 load+stage; full drain once.
    ISSUE_B_DMA(0, 0);
    __builtin_amdgcn_sched_barrier(0);
    ISSUE_A(0);
    STAGE_A(aL);
    asm volatile("s_waitcnt vmcnt(0) lgkmcnt(0)" ::: "memory");
    __builtin_amdgcn_s_barrier();
    __builtin_amdgcn_sched_barrier(0);

    for (int g = 0; g < NG1; ++g) {
        char* aCur = aL + (g & 1) * 16384;
        char* aNxt = aL + ((g & 1) ^ 1) * 16384;
        const bool more = (g + 1 < NG1);
        const int kt = 2 * g;

        // s = 0: B(kt+1) DMA (pinned first), A(g+1) prefetch, compute kt.
        ISSUE_B_DMA(kt + 1, (kt + 1) & 1);
        __builtin_amdgcn_sched_barrier(0);
        if (more) ISSUE_A(g + 1);
        COMPUTE(aCur, 0, kt & 1);
        // counted barrier: B's 4 DMAs done; A's 8 loads stay in flight.
        if (more) asm volatile("s_waitcnt vmcnt(8)" ::: "memory");
        else      asm volatile("s_waitcnt vmcnt(0)" ::: "memory");
        __builtin_amdgcn_s_barrier();
        __builtin_amdgcn_sched_barrier(0);

        // s = 1: B(kt+2) DMA, compute kt+1, stage A(g+1); drain.
        if (more) ISSUE_B_DMA(kt + 2, (kt + 2) & 1);
        __builtin_amdgcn_sched_barrier(0);
        COMPUTE(aCur, 1, (kt + 1) & 1);
        if (more) STAGE_A(aNxt);
        asm volatile("s_waitcnt vmcnt(0) lgkmcnt(0)" ::: "memory");
        __builtin_amdgcn_s_barrier();
        __builtin_amdgcn_sched_barrier(0);
    }

    // partial degree: 8-lane shfl tree, plain store per row
    dsum[0] += __shfl_xor(dsum[0], 1, 64);
    dsum[0] += __shfl_xor(dsum[0], 2, 64);
    dsum[0] += __shfl_xor(dsum[0], 4, 64);
    dsum[1] += __shfl_xor(dsum[1], 1, 64);
    dsum[1] += __shfl_xor(dsum[1], 2, 64);
    dsum[1] += __shfl_xor(dsum[1], 4, 64);
    float* degp = deg01 + (size_t)half * NN;
    if (asl == 0) {
        degp[row0 + ra0] = dsum[0];
        degp[row0 + ra0 + 32] = dsum[1];
    }

    // partial S -> plain coalesced stores into this half's buffer
    float* Sp = S01 + (size_t)half * NN * 128;
#pragma unroll
    for (int ms = 0; ms < 2; ++ms)
#pragma unroll
        for (int ns = 0; ns < 4; ++ns)
#pragma unroll
            for (int j = 0; j < 4; ++j) {
                int r = mt * 32 + ms * 16 + (lane >> 4) * 4 + j;
                int c = nt * 64 + ns * 16 + (lane & 15);
                Sp[(row0 + r) * 128 + c] = acc[ms][ns][j];
            }
}

// K2: out = [feat | (S0+S1)/(deg0+deg1+1)] @ W^T -> d_out.
__global__ __launch_bounds__(256) void sage_epilogue(
    const float* __restrict__ feat,
    const float* __restrict__ W,
    const float* __restrict__ S01,
    const float* __restrict__ deg01,
    float* __restrict__ out)
{
    __shared__ __align__(16) char smem[33024];
    char* dL = smem;                       // [64][512 B] bf16 swizzled
    float* degp = (float*)(smem + 32768);  // [64]

    const int t = threadIdx.x;
    const int lane = t & 63;
    const int wv = t >> 6;
    const int mt = wv >> 1;
    const int nt = wv & 1;
    const size_t row0 = (size_t)blockIdx.x * BM;

    if (t < 64) degp[t] = deg01[row0 + t] + deg01[NN + row0 + t];

    // feat -> cols [0,128)
#pragma unroll
    for (int i = 0; i < 8; ++i) {
        int idx = i * 256 + t;
        int r = idx >> 5;
        int s = idx & 31;
        f32x4 v = *(const f32x4*)(feat + (row0 + r) * 128 + s * 4);
        u16x4 p; p.x = f2bf(v[0]); p.y = f2bf(v[1]); p.z = f2bf(v[2]); p.w = f2bf(v[3]);
        int off = (r * 512 + s * 8) ^ ((r & 7) << 4);
        *(u16x4*)(dL + off) = p;
    }
    __syncthreads();   // degp visible

    // (S0+S1)/(deg+1) -> cols [128,256)
#pragma unroll
    for (int i = 0; i < 8; ++i) {
        int idx = i * 256 + t;
        int r = idx >> 5;
        int s = idx & 31;
        size_t o = (row0 + r) * 128 + s * 4;
        f32x4 v0 = *(const f32x4*)(S01 + o);
        f32x4 v1 = *(const f32x4*)(S01 + (size_t)NN * 128 + o);
        float inv = 1.0f / (degp[r] + 1.0f);
        u16x4 p;
        p.x = f2bf((v0[0] + v1[0]) * inv); p.y = f2bf((v0[1] + v1[1]) * inv);
        p.z = f2bf((v0[2] + v1[2]) * inv); p.w = f2bf((v0[3] + v1[3]) * inv);
        int off = (r * 512 + 256 + s * 8) ^ ((r & 7) << 4);
        *(u16x4*)(dL + off) = p;
    }
    __syncthreads();

    f32x4 acc2[2][4];
#pragma unroll
    for (int i = 0; i < 2; ++i)
#pragma unroll
        for (int j = 0; j < 4; ++j) acc2[i][j] = (f32x4){0.f, 0.f, 0.f, 0.f};

#pragma unroll
    for (int ks = 0; ks < 8; ++ks) {
        bf16x8 af[2], bfr[4];
#pragma unroll
        for (int ms = 0; ms < 2; ++ms) {
            int r = mt * 32 + ms * 16 + (lane & 15);
            int off = r * 512 + ((ks * 64 + (lane >> 4) * 16) ^ ((r & 7) << 4));
            af[ms] = *(const bf16x8*)(dL + off);
        }
#pragma unroll
        for (int ns = 0; ns < 4; ++ns) {
            int c = nt * 64 + ns * 16 + (lane & 15);
            int k0 = ks * 32 + (lane >> 4) * 8;
            f32x4 w0 = *(const f32x4*)(W + (size_t)c * 256 + k0);
            f32x4 w1 = *(const f32x4*)(W + (size_t)c * 256 + k0 + 4);
            u16x8 p;
            p[0] = f2bf(w0[0]); p[1] = f2bf(w0[1]); p[2] = f2bf(w0[2]); p[3] = f2bf(w0[3]);
            p[4] = f2bf(w1[0]); p[5] = f2bf(w1[1]); p[6] = f2bf(w1[2]); p[7] = f2bf(w1[3]);
            bfr[ns] = __builtin_bit_cast(bf16x8, p);
        }
#pragma unroll
        for (int ms = 0; ms < 2; ++ms)
#pragma unroll
            for (int ns = 0; ns < 4; ++ns)
                acc2[ms][ns] = MFMA16(af[ms], bfr[ns], acc2[ms][ns]);
    }

#pragma unroll
    for (int ms = 0; ms < 2; ++ms)
#pragma unroll
        for (int ns = 0; ns < 4; ++ns)
#pragma unroll
            for (int j = 0; j < 4; ++j) {
                int r = mt * 32 + ms * 16 + (lane >> 4) * 4 + j;
                int c = nt * 64 + ns * 16 + (lane & 15);
                out[(row0 + r) * 128 + c] = acc2[ms][ns][j];
            }
}

extern "C" void kernel_launch(void* const* d_in, const int* in_sizes, int n_in,
                              void* d_out, int out_size, void* d_ws, size_t ws_size,
                              hipStream_t stream) {
    const float* adj = (const float*)d_in[0];
    const float* feat = (const float*)d_in[1];
    const float* neigh = (const float*)d_in[2];
    const float* W = (const float*)d_in[3];
    float* out = (float*)d_out;

    // ws layout: neighT 4 MiB | deg01 2*64 KiB | pad | S01 2*8 MiB
    unsigned short* neighT = (unsigned short*)d_ws;
    float* deg01 = (float*)((char*)d_ws + (size_t)4 * 1024 * 1024);
    float* S01 = (float*)((char*)d_ws + (size_t)8 * 1024 * 1024);

    prep_transpose<<<NN / 64, 256, 0, stream>>>(neigh, neighT);
    sage_partial<<<(NN / BM) * 2, 256, 0, stream>>>(adj, neighT, S01, deg01);
    sage_epilogue<<<NN / BM, 256, 0, stream>>>(feat, W, S01, deg01, out);
}